// Round 1
// baseline (329.453 us; speedup 1.0000x reference)
//
#include <hip/hip_runtime.h>

// ---------------- problem constants ----------------
#define DIMK   8192
#define NPER   512          // N
#define HH     4            // H
#define NROWS  2048         // H*N
#define NCOLS  128          // inner = HEADS*DH
#define KSPLIT 8
#define KCHUNK 1024         // DIMK / KSPLIT
#define SLICE_ELEMS 4194304.0  // 512*8192

// ---------------- ws layout (bytes) ----------------
static const size_t STATS_OFF = 0;                                   // 16 doubles (sum,sumsq x 8 slices)
static const size_t P_OFF     = 256;
static const size_t P_BYTES   = (size_t)2 * KSPLIT * NROWS * NCOLS * 4;  // 16 MB
static const size_t OUT2_OFF  = P_OFF + P_BYTES;                     // 512*512 f32
static const size_t IPSUM_OFF = OUT2_OFF + (size_t)512 * 512 * 4;    // 4*512 f32
static const size_t CTXB_OFF  = IPSUM_OFF + (size_t)4 * 512 * 4;     // 2048*64 f32
static const size_t O2_OFF    = CTXB_OFF + (size_t)2048 * 64 * 4;    // 512 f32
static const size_t WS_NEED   = O2_OFF + (size_t)512 * 4;

// ---------------- K1: LN statistics ----------------
// grid 2048: slice = bid>>8 (t*4+h), chunk = bid&255 (16384 elems each)
__global__ __launch_bounds__(256) void k_stats(const float* __restrict__ pic,
                                               const float* __restrict__ ctx,
                                               double* __restrict__ stats) {
  int b = blockIdx.x;
  int s = b >> 8;          // 0..7
  int c = b & 255;
  int t = s >> 2, h = s & 3;
  const float* base = (t ? ctx : pic) + (size_t)h * NPER * DIMK + (size_t)c * 16384;
  const float4* p4 = reinterpret_cast<const float4*>(base);
  int tid = threadIdx.x;
  float sum = 0.f, sq = 0.f;
#pragma unroll
  for (int i = 0; i < 16; ++i) {
    float4 v = p4[tid + 256 * i];
    sum += (v.x + v.y) + (v.z + v.w);
    sq  += (v.x * v.x + v.y * v.y) + (v.z * v.z + v.w * v.w);
  }
#pragma unroll
  for (int d = 1; d < 64; d <<= 1) {
    sum += __shfl_xor(sum, d);
    sq  += __shfl_xor(sq, d);
  }
  __shared__ float ps[4], pq[4];
  int w = tid >> 6;
  if ((tid & 63) == 0) { ps[w] = sum; pq[w] = sq; }
  __syncthreads();
  if (tid == 0) {
    double S = (double)ps[0] + (double)ps[1] + (double)ps[2] + (double)ps[3];
    double Q = (double)pq[0] + (double)pq[1] + (double)pq[2] + (double)pq[3];
    atomicAdd(&stats[2 * s], S);
    atomicAdd(&stats[2 * s + 1], Q);
  }
}

// ---------------- K2: fused LN+spike+GEMM (split-K partials) ----------------
// grid (16 row-tiles, 8 k-splits, 2 tensors), 512 threads
// BM=128 rows x BN=128 cols, BK=32, per-thread 4x8 micro-tile
__global__ __launch_bounds__(512) void k_gemm(const float* __restrict__ pic,
                                              const float* __restrict__ ctxin,
                                              const float* __restrict__ gamma,
                                              const float* __restrict__ lnbeta,
                                              const float* __restrict__ Wp,
                                              const float* __restrict__ Wc,
                                              const double* __restrict__ stats,
                                              float* __restrict__ P) {
  const int tid = threadIdx.x;
  const int bx = blockIdx.x;   // row tile
  const int ky = blockIdx.y;   // k split
  const int t  = blockIdx.z;   // 0=pic, 1=ctx
  const float* A = t ? ctxin : pic;
  const float* W = t ? Wc : Wp;

  const int h = bx >> 2;                 // 128-row tiles: 4 per h
  const int sidx = t * 4 + h;
  double su = stats[2 * sidx], qu = stats[2 * sidx + 1];
  double dmean = su * (1.0 / SLICE_ELEMS);
  float mean = (float)dmean;
  float var  = (float)(qu * (1.0 / SLICE_ELEMS) - dmean * dmean);
  float rstd = rsqrtf(var + 1e-5f);

  __shared__ __align__(16) float As[32][132];
  __shared__ __align__(16) float Bs[32][132];

  const int row0 = bx * 128;
  const int lr = tid >> 3;            // 0..63
  const int lk = (tid & 7) << 2;      // 0,4,...,28
  const int tr = tid >> 4;            // 0..31
  const int tc = tid & 15;            // 0..15

  float acc[4][8];
#pragma unroll
  for (int i = 0; i < 4; ++i)
#pragma unroll
    for (int j = 0; j < 8; ++j) acc[i][j] = 0.f;

  for (int it = 0; it < KCHUNK / 32; ++it) {
    const int kb = ky * KCHUNK + it * 32;
    __syncthreads();
    {
      const float4 g4 = *(const float4*)(gamma  + kb + lk);
      const float4 b4 = *(const float4*)(lnbeta + kb + lk);
#pragma unroll
      for (int l = 0; l < 2; ++l) {
        const int r = lr + l * 64;
        const float4 av = *(const float4*)(A + (size_t)(row0 + r) * DIMK + kb + lk);
        As[lk + 0][r] = ((av.x - mean) * rstd * g4.x + b4.x) > 1.0f ? 1.0f : 0.0f;
        As[lk + 1][r] = ((av.y - mean) * rstd * g4.y + b4.y) > 1.0f ? 1.0f : 0.0f;
        As[lk + 2][r] = ((av.z - mean) * rstd * g4.z + b4.z) > 1.0f ? 1.0f : 0.0f;
        As[lk + 3][r] = ((av.w - mean) * rstd * g4.w + b4.w) > 1.0f ? 1.0f : 0.0f;
        const float4 wv = *(const float4*)(W + (size_t)r * DIMK + kb + lk);
        Bs[lk + 0][r] = wv.x;
        Bs[lk + 1][r] = wv.y;
        Bs[lk + 2][r] = wv.z;
        Bs[lk + 3][r] = wv.w;
      }
    }
    __syncthreads();
#pragma unroll
    for (int kk = 0; kk < 32; ++kk) {
      float a[4], bb[8];
      *(float4*)a        = *(const float4*)&As[kk][tr * 4];
      *(float4*)(bb)     = *(const float4*)&Bs[kk][tc * 8];
      *(float4*)(bb + 4) = *(const float4*)&Bs[kk][tc * 8 + 4];
#pragma unroll
      for (int i = 0; i < 4; ++i)
#pragma unroll
        for (int j = 0; j < 8; ++j) acc[i][j] += a[i] * bb[j];
    }
  }

  float* Pt = P + ((size_t)(t * KSPLIT + ky) * NROWS + row0) * NCOLS;
#pragma unroll
  for (int i = 0; i < 4; ++i) {
    const int r = tr * 4 + i;
    float4 v0 = make_float4(acc[i][0], acc[i][1], acc[i][2], acc[i][3]);
    float4 v1 = make_float4(acc[i][4], acc[i][5], acc[i][6], acc[i][7]);
    *(float4*)&Pt[(size_t)r * NCOLS + tc * 8]     = v0;
    *(float4*)&Pt[(size_t)r * NCOLS + tc * 8 + 4] = v1;
  }
}

// ---------------- K3: per-row epilogue (bias, scale, softmax-attn) ----------------
// grid 2048 (one block per (h,n) row), 128 threads (o index)
__global__ __launch_bounds__(128) void k_row(const float* __restrict__ P,
                                             const float* __restrict__ b_pic,
                                             const float* __restrict__ b_ctx,
                                             float* __restrict__ out2,
                                             float* __restrict__ ipsum,
                                             float* __restrict__ ctxbuf) {
  const int r = blockIdx.x;
  const int o = threadIdx.x;
  float ipv = b_pic[o];
  float cv  = b_ctx[o];
#pragma unroll
  for (int ks = 0; ks < KSPLIT; ++ks) {
    ipv += P[((size_t)ks * NROWS + r) * NCOLS + o];
    cv  += P[((size_t)(KSPLIT + ks) * NROWS + r) * NCOLS + o];
  }
  ipv *= 0.125f;  // SCALE = 64^-0.5

  __shared__ float sh[4];
  __shared__ float sh2[2];
  const int w = o >> 6;

  // ic_s (sum of cv over o<64) and v_s (o>=64); ip row sum
  float cs = cv;
  float is = ipv;
#pragma unroll
  for (int d = 1; d < 64; d <<= 1) {
    cs += __shfl_xor(cs, d);
    is += __shfl_xor(is, d);
  }
  if ((o & 63) == 0) { sh[w] = cs; sh[2 + w] = is; }
  __syncthreads();
  const float ic_s = sh[0];
  const float v_s  = sh[1];
  const float ips  = sh[2] + sh[3];
  if (o == 0) ipsum[r] = ips;

  const float sim = ipv * ic_s;
  // softmax over the 128 lanes
  float m = sim;
#pragma unroll
  for (int d = 1; d < 64; d <<= 1) m = fmaxf(m, __shfl_xor(m, d));
  if ((o & 63) == 0) sh2[w] = m;
  __syncthreads();
  m = fmaxf(sh2[0], sh2[1]);
  const float e = __expf(sim - m);
  float es = e;
#pragma unroll
  for (int d = 1; d < 64; d <<= 1) es += __shfl_xor(es, d);
  if ((o & 63) == 0) sh[w] = es;   // safe: all sh reads happened before prior sync
  __syncthreads();
  const float denom = sh[0] + sh[1];
  const float outv = (e / denom) * v_s;

  const int hh = r >> 9, n = r & 511;
  out2[(size_t)n * 512 + hh * 128 + o] = outv;
  if (o < 64) ctxbuf[(size_t)r * 64 + o] = cv;
}

// ---------------- K4: conv1+conv2 collapsed to w_eff, then o2 ----------------
// single block, 512 threads
__global__ __launch_bounds__(512) void k_mid(const float* __restrict__ out2,
                                             const float* __restrict__ c1w,
                                             const float* __restrict__ c1b,
                                             const float* __restrict__ c2w,
                                             const float* __restrict__ c2b,
                                             float* __restrict__ o2buf) {
  const int tid = threadIdx.x;
  __shared__ float weff[512];
  float wacc = 0.f;
#pragma unroll
  for (int o = 0; o < 32; ++o) wacc += c2w[o] * c1w[o * 512 + tid];
  weff[tid] = wacc;
  float beff = c2b[0];
#pragma unroll
  for (int o = 0; o < 32; ++o) beff += c2w[o] * c1b[o];
  __syncthreads();
  float acc = 0.f;
  for (int n = 0; n < 512; ++n) acc += out2[(size_t)n * 512 + tid] * weff[n];
  o2buf[tid] = acc + beff;
}

// ---------------- K5: fc matvec + ip_sum broadcast + interp + relu + ic_sum ----------------
// grid 512 (row i), 64 threads (output col j)
__global__ __launch_bounds__(64) void k_final(const float* __restrict__ o2buf,
                                              const float* __restrict__ fcw,
                                              const float* __restrict__ fcb,
                                              const float* __restrict__ ipsum,
                                              const float* __restrict__ ctxbuf,
                                              float* __restrict__ out) {
  const int i = blockIdx.x;
  const int j = threadIdx.x;
  float a = 0.f;
#pragma unroll
  for (int u = 0; u < 8; ++u) {
    const int k = j * 8 + u;
    a += o2buf[k] * fcw[(size_t)i * 512 + k];
  }
#pragma unroll
  for (int d = 1; d < 64; d <<= 1) a += __shfl_xor(a, d);
  const float o3 = a + fcb[i];

  float src = (j + 0.5f) * (4.0f / 64.0f) - 0.5f;
  src = fmaxf(src, 0.0f);
  int i0 = (int)floorf(src);
  if (i0 > 3) i0 = 3;
  const int i1 = (i0 + 1 < 3) ? i0 + 1 : 3;
  const float w = src - (float)i0;

  const float v0 = o3 + ipsum[i0 * 512 + i];
  const float v1 = o3 + ipsum[i1 * 512 + i];
  float v = v0 * (1.0f - w) + v1 * w;
  v = fmaxf(v, 0.0f);

  float ics = 0.f;
#pragma unroll
  for (int hh2 = 0; hh2 < 4; ++hh2) ics += ctxbuf[((size_t)hh2 * 512 + i) * 64 + j];
  out[(size_t)i * 64 + j] = fmaxf(v + ics, 0.0f);
}

// ---------------- launch ----------------
extern "C" void kernel_launch(void* const* d_in, const int* in_sizes, int n_in,
                              void* d_out, int out_size, void* d_ws, size_t ws_size,
                              hipStream_t stream) {
  const float* pic    = (const float*)d_in[0];
  const float* ctx    = (const float*)d_in[1];
  const float* gamma  = (const float*)d_in[2];
  const float* lnbeta = (const float*)d_in[3];
  const float* Wp     = (const float*)d_in[4];
  const float* bp     = (const float*)d_in[5];
  const float* Wc     = (const float*)d_in[6];
  const float* bc     = (const float*)d_in[7];
  const float* c1w    = (const float*)d_in[8];
  const float* c1b    = (const float*)d_in[9];
  const float* c2w    = (const float*)d_in[10];
  const float* c2b    = (const float*)d_in[11];
  const float* fcw    = (const float*)d_in[12];
  const float* fcb    = (const float*)d_in[13];
  float* out = (float*)d_out;

  if (ws_size < WS_NEED) return;  // scratch too small: fail visibly (output stays poisoned)

  char* ws = (char*)d_ws;
  double* stats = (double*)(ws + STATS_OFF);
  float* P      = (float*)(ws + P_OFF);
  float* out2   = (float*)(ws + OUT2_OFF);
  float* ipsum  = (float*)(ws + IPSUM_OFF);
  float* ctxbuf = (float*)(ws + CTXB_OFF);
  float* o2buf  = (float*)(ws + O2_OFF);

  hipMemsetAsync(stats, 0, 128, stream);
  k_stats<<<2048, 256, 0, stream>>>(pic, ctx, stats);
  k_gemm<<<dim3(16, KSPLIT, 2), 512, 0, stream>>>(pic, ctx, gamma, lnbeta, Wp, Wc, stats, P);
  k_row<<<NROWS, 128, 0, stream>>>(P, bp, bc, out2, ipsum, ctxbuf);
  k_mid<<<1, 512, 0, stream>>>(out2, c1w, c1b, c2w, c2b, o2buf);
  k_final<<<512, 64, 0, stream>>>(o2buf, fcw, fcb, ipsum, ctxbuf, out);
}

// Round 2
// 245.837 us; speedup vs baseline: 1.3401x; 1.3401x over previous
//
#include <hip/hip_runtime.h>

typedef unsigned short ushort;
typedef unsigned int uint;
typedef __attribute__((ext_vector_type(8))) short short8v;
typedef __attribute__((ext_vector_type(4))) float floatx4;

// ---------------- problem constants ----------------
#define DIMK   8192
#define NPER   512
#define NROWS  2048
#define NCOLS  128
#define KSPLIT 8
#define KCHUNK 1024          // DIMK / KSPLIT
#define BK     64
#define NIT    16            // KCHUNK / BK
#define SLICE_ELEMS 4194304.0

// ---------------- ws layout (bytes) ----------------
static const size_t STATS_OFF = 0;                                    // 16 doubles
static const size_t WB_OFF    = 256;
static const size_t WB_BYTES  = (size_t)2 * 128 * DIMK * 2;           // 4 MB bf16 weights
static const size_t P_OFF     = WB_OFF + WB_BYTES;
static const size_t P_BYTES   = (size_t)2 * KSPLIT * NROWS * NCOLS * 4;  // 16 MB
static const size_t OUT2_OFF  = P_OFF + P_BYTES;                      // 512*512 f32
static const size_t IPSUM_OFF = OUT2_OFF + (size_t)512 * 512 * 4;     // 4*512 f32
static const size_t CTXB_OFF  = IPSUM_OFF + (size_t)4 * 512 * 4;      // 2048*64 f32
static const size_t O2_OFF    = CTXB_OFF + (size_t)2048 * 64 * 4;     // 512 f32
static const size_t WS_NEED   = O2_OFF + (size_t)512 * 4;

__device__ __forceinline__ ushort f2bf(float x) {   // RNE f32->bf16
  uint u = __float_as_uint(x);
  return (ushort)((u + 0x7FFFu + ((u >> 16) & 1u)) >> 16);
}

// ---------------- K0: W f32 -> bf16 ----------------
__global__ __launch_bounds__(256) void k_wconv(const float* __restrict__ Wp,
                                               const float* __restrict__ Wc,
                                               ushort* __restrict__ Wb) {
  const size_t i = ((size_t)blockIdx.x * 256 + threadIdx.x) * 8;  // 0..2M, 8 per thread
  const size_t HALF = (size_t)128 * DIMK;                          // 1,048,576 (mult of 8)
  const float* src = (i < HALF) ? (Wp + i) : (Wc + (i - HALF));
  float4 a = *(const float4*)src;
  float4 b = *(const float4*)(src + 4);
  short8v v;
  v[0] = (short)f2bf(a.x); v[1] = (short)f2bf(a.y);
  v[2] = (short)f2bf(a.z); v[3] = (short)f2bf(a.w);
  v[4] = (short)f2bf(b.x); v[5] = (short)f2bf(b.y);
  v[6] = (short)f2bf(b.z); v[7] = (short)f2bf(b.w);
  *(short8v*)&Wb[i] = v;
}

// ---------------- K1: LN statistics ----------------
__global__ __launch_bounds__(256) void k_stats(const float* __restrict__ pic,
                                               const float* __restrict__ ctx,
                                               double* __restrict__ stats) {
  int b = blockIdx.x;
  int s = b >> 8;
  int c = b & 255;
  int t = s >> 2, h = s & 3;
  const float* base = (t ? ctx : pic) + (size_t)h * NPER * DIMK + (size_t)c * 16384;
  const float4* p4 = reinterpret_cast<const float4*>(base);
  int tid = threadIdx.x;
  float sum = 0.f, sq = 0.f;
#pragma unroll
  for (int i = 0; i < 16; ++i) {
    float4 v = p4[tid + 256 * i];
    sum += (v.x + v.y) + (v.z + v.w);
    sq  += (v.x * v.x + v.y * v.y) + (v.z * v.z + v.w * v.w);
  }
#pragma unroll
  for (int d = 1; d < 64; d <<= 1) {
    sum += __shfl_xor(sum, d);
    sq  += __shfl_xor(sq, d);
  }
  __shared__ float ps[4], pq[4];
  int w = tid >> 6;
  if ((tid & 63) == 0) { ps[w] = sum; pq[w] = sq; }
  __syncthreads();
  if (tid == 0) {
    double S = (double)ps[0] + (double)ps[1] + (double)ps[2] + (double)ps[3];
    double Q = (double)pq[0] + (double)pq[1] + (double)pq[2] + (double)pq[3];
    atomicAdd(&stats[2 * s], S);
    atomicAdd(&stats[2 * s + 1], Q);
  }
}

// ---------------- K2: fused LN+spike+MFMA GEMM (split-K partials) ----------------
// grid (16 row-tiles, KSPLIT, 2 tensors), 256 threads = 4 waves (2x2 of 64x64)
__global__ __launch_bounds__(256) void k_gemm(const float* __restrict__ pic,
                                              const float* __restrict__ ctxin,
                                              const float* __restrict__ gamma,
                                              const float* __restrict__ lnbeta,
                                              const ushort* __restrict__ Wb,
                                              const double* __restrict__ stats,
                                              float* __restrict__ P) {
  const int tid  = threadIdx.x;
  const int lane = tid & 63;
  const int wv   = tid >> 6;
  const int wm   = wv >> 1, wn = wv & 1;
  const int bx = blockIdx.x, ky = blockIdx.y, t = blockIdx.z;
  const float*  A  = t ? ctxin : pic;
  const ushort* Wt = Wb + (size_t)t * 128 * DIMK;
  const int row0 = bx * 128;

  const int sidx = t * 4 + (bx >> 2);
  double su = stats[2 * sidx], qu = stats[2 * sidx + 1];
  double dmean = su * (1.0 / SLICE_ELEMS);
  const float mean = (float)dmean;
  const float var  = (float)(qu * (1.0 / SLICE_ELEMS) - dmean * dmean);
  const float rstd = rsqrtf(var + 1e-5f);

  __shared__ __align__(16) ushort Asl[2][128 * BK];   // 16 KB x2
  __shared__ __align__(16) ushort Wsl[2][128 * BK];   // 16 KB x2

  const int k8 = tid & 7;        // which 8-elem k chunk
  const int r0 = tid >> 3;       // base row (0..31), +c*32

  // fragment LDS offsets (elements); XOR swizzle: elem ^ ((row&7)<<3)  == byte ^ ((row&7)<<4)
  const int kg8 = (lane >> 4) << 3;
  int abase[4], axor[4], bbase[4], bxor[4];
#pragma unroll
  for (int m = 0; m < 4; ++m) {
    int ra = wm * 64 + m * 16 + (lane & 15);
    abase[m] = ra * BK; axor[m] = (ra & 7) << 3;
    int rb = wn * 64 + m * 16 + (lane & 15);
    bbase[m] = rb * BK; bxor[m] = (rb & 7) << 3;
  }

  floatx4 acc[4][4];
  floatx4 zz = {0.f, 0.f, 0.f, 0.f};
#pragma unroll
  for (int m = 0; m < 4; ++m)
#pragma unroll
    for (int n = 0; n < 4; ++n) acc[m][n] = zz;

  float4 xa[4][2]; uint4 xw[4];
  float4 g0, g1, bb0, bb1;

  auto LOAD = [&](int it) {
    const int kb = ky * KCHUNK + it * BK;
    const float* gp = gamma  + kb + k8 * 8;
    const float* bp = lnbeta + kb + k8 * 8;
    g0 = *(const float4*)gp;  g1 = *(const float4*)(gp + 4);
    bb0 = *(const float4*)bp; bb1 = *(const float4*)(bp + 4);
#pragma unroll
    for (int c = 0; c < 4; ++c) {
      const int r = r0 + c * 32;
      const float* ap = A + (size_t)(row0 + r) * DIMK + kb + k8 * 8;
      xa[c][0] = *(const float4*)ap;
      xa[c][1] = *(const float4*)(ap + 4);
      xw[c] = *(const uint4*)(Wt + (size_t)r * DIMK + kb + k8 * 8);
    }
  };

  auto WRITE = [&](int buf) {
#pragma unroll
    for (int c = 0; c < 4; ++c) {
      const int r = r0 + c * 32;
      float xs[8] = {xa[c][0].x, xa[c][0].y, xa[c][0].z, xa[c][0].w,
                     xa[c][1].x, xa[c][1].y, xa[c][1].z, xa[c][1].w};
      float gs[8] = {g0.x, g0.y, g0.z, g0.w, g1.x, g1.y, g1.z, g1.w};
      float bs[8] = {bb0.x, bb0.y, bb0.z, bb0.w, bb1.x, bb1.y, bb1.z, bb1.w};
      short8v sv;
#pragma unroll
      for (int j = 0; j < 8; ++j)
        sv[j] = (short)(((xs[j] - mean) * rstd * gs[j] + bs[j] > 1.0f) ? 0x3F80 : 0);
      const int off = r * BK + ((k8 * 8) ^ ((r & 7) << 3));
      *(short8v*)&Asl[buf][off] = sv;
      *(uint4*)&Wsl[buf][off]   = xw[c];
    }
  };

  auto COMPUTE = [&](int buf) {
#pragma unroll
    for (int ks = 0; ks < 2; ++ks) {
      short8v af[4], bfr[4];
#pragma unroll
      for (int m = 0; m < 4; ++m)
        af[m] = *(const short8v*)&Asl[buf][abase[m] + ((ks * 32 + kg8) ^ axor[m])];
#pragma unroll
      for (int n = 0; n < 4; ++n)
        bfr[n] = *(const short8v*)&Wsl[buf][bbase[n] + ((ks * 32 + kg8) ^ bxor[n])];
#pragma unroll
      for (int m = 0; m < 4; ++m)
#pragma unroll
        for (int n = 0; n < 4; ++n)
          acc[m][n] = __builtin_amdgcn_mfma_f32_16x16x32_bf16(af[m], bfr[n], acc[m][n], 0, 0, 0);
    }
  };

  LOAD(0);
  WRITE(0);
  __syncthreads();
#pragma unroll 2
  for (int it = 0; it < NIT - 1; ++it) {
    LOAD(it + 1);          // issue next tile's global loads early (overlap MFMA)
    COMPUTE(it & 1);
    __syncthreads();
    WRITE((it + 1) & 1);   // compiler inserts vmcnt wait here
    __syncthreads();
  }
  COMPUTE((NIT - 1) & 1);

  // C/D layout: col = lane&15, row = (lane>>4)*4 + j  [m89-verified]
  float* Pt = P + ((size_t)(t * KSPLIT + ky) * NROWS + row0) * NCOLS;
#pragma unroll
  for (int m = 0; m < 4; ++m) {
    const int gr = wm * 64 + m * 16 + ((lane >> 4) << 2);
#pragma unroll
    for (int n = 0; n < 4; ++n) {
      const int gc = wn * 64 + n * 16 + (lane & 15);
#pragma unroll
      for (int j = 0; j < 4; ++j)
        Pt[(size_t)(gr + j) * NCOLS + gc] = acc[m][n][j];
    }
  }
}

// ---------------- K3: per-row epilogue (bias, scale, softmax-attn) ----------------
__global__ __launch_bounds__(128) void k_row(const float* __restrict__ P,
                                             const float* __restrict__ b_pic,
                                             const float* __restrict__ b_ctx,
                                             float* __restrict__ out2,
                                             float* __restrict__ ipsum,
                                             float* __restrict__ ctxbuf) {
  const int r = blockIdx.x;
  const int o = threadIdx.x;
  float ipv = b_pic[o];
  float cv  = b_ctx[o];
#pragma unroll
  for (int ks = 0; ks < KSPLIT; ++ks) {
    ipv += P[((size_t)ks * NROWS + r) * NCOLS + o];
    cv  += P[((size_t)(KSPLIT + ks) * NROWS + r) * NCOLS + o];
  }
  ipv *= 0.125f;

  __shared__ float sh[4];
  __shared__ float sh2[2];
  const int w = o >> 6;

  float cs = cv;
  float is = ipv;
#pragma unroll
  for (int d = 1; d < 64; d <<= 1) {
    cs += __shfl_xor(cs, d);
    is += __shfl_xor(is, d);
  }
  if ((o & 63) == 0) { sh[w] = cs; sh[2 + w] = is; }
  __syncthreads();
  const float ic_s = sh[0];
  const float v_s  = sh[1];
  const float ips  = sh[2] + sh[3];
  if (o == 0) ipsum[r] = ips;

  const float sim = ipv * ic_s;
  float m = sim;
#pragma unroll
  for (int d = 1; d < 64; d <<= 1) m = fmaxf(m, __shfl_xor(m, d));
  if ((o & 63) == 0) sh2[w] = m;
  __syncthreads();
  m = fmaxf(sh2[0], sh2[1]);
  const float e = __expf(sim - m);
  float es = e;
#pragma unroll
  for (int d = 1; d < 64; d <<= 1) es += __shfl_xor(es, d);
  if ((o & 63) == 0) sh[w] = es;
  __syncthreads();
  const float denom = sh[0] + sh[1];
  const float outv = (e / denom) * v_s;

  const int hh = r >> 9, n = r & 511;
  out2[(size_t)n * 512 + hh * 128 + o] = outv;
  if (o < 64) ctxbuf[(size_t)r * 64 + o] = cv;
}

// ---------------- K4: conv chain as w_eff matvec (8 blocks, atomic) ----------------
__global__ __launch_bounds__(512) void k_mid(const float* __restrict__ out2,
                                             const float* __restrict__ c1w,
                                             const float* __restrict__ c1b,
                                             const float* __restrict__ c2w,
                                             const float* __restrict__ c2b,
                                             float* __restrict__ o2buf) {
  const int b = blockIdx.x;      // n range [b*64, b*64+64)
  const int tid = threadIdx.x;   // l = 0..511
  __shared__ float wsh[64];
  __shared__ float c2s[32];
  if (tid < 32) c2s[tid] = c2w[tid];
  __syncthreads();
  if (tid < 64) {
    const int n = b * 64 + tid;
    float a = 0.f;
#pragma unroll
    for (int o = 0; o < 32; ++o) a += c2s[o] * c1w[o * 512 + n];
    wsh[tid] = a;
  }
  __syncthreads();
  float acc = 0.f;
#pragma unroll 8
  for (int u = 0; u < 64; ++u)
    acc += out2[(size_t)(b * 64 + u) * 512 + tid] * wsh[u];
  if (b == 0) {
    float beff = c2b[0];
#pragma unroll
    for (int o = 0; o < 32; ++o) beff += c2s[o] * c1b[o];
    acc += beff;
  }
  atomicAdd(&o2buf[tid], acc);
}

// ---------------- K5: fc matvec + broadcast + interp + relu + ic_sum ----------------
__global__ __launch_bounds__(64) void k_final(const float* __restrict__ o2buf,
                                              const float* __restrict__ fcw,
                                              const float* __restrict__ fcb,
                                              const float* __restrict__ ipsum,
                                              const float* __restrict__ ctxbuf,
                                              float* __restrict__ out) {
  const int i = blockIdx.x;
  const int j = threadIdx.x;
  float a = 0.f;
#pragma unroll
  for (int u = 0; u < 8; ++u) {
    const int k = j * 8 + u;
    a += o2buf[k] * fcw[(size_t)i * 512 + k];
  }
#pragma unroll
  for (int d = 1; d < 64; d <<= 1) a += __shfl_xor(a, d);
  const float o3 = a + fcb[i];

  float src = (j + 0.5f) * (4.0f / 64.0f) - 0.5f;
  src = fmaxf(src, 0.0f);
  int i0 = (int)floorf(src);
  if (i0 > 3) i0 = 3;
  const int i1 = (i0 + 1 < 3) ? i0 + 1 : 3;
  const float w = src - (float)i0;

  const float v0 = o3 + ipsum[i0 * 512 + i];
  const float v1 = o3 + ipsum[i1 * 512 + i];
  float v = v0 * (1.0f - w) + v1 * w;
  v = fmaxf(v, 0.0f);

  float ics = 0.f;
#pragma unroll
  for (int hh2 = 0; hh2 < 4; ++hh2) ics += ctxbuf[((size_t)hh2 * 512 + i) * 64 + j];
  out[(size_t)i * 64 + j] = fmaxf(v + ics, 0.0f);
}

// ---------------- launch ----------------
extern "C" void kernel_launch(void* const* d_in, const int* in_sizes, int n_in,
                              void* d_out, int out_size, void* d_ws, size_t ws_size,
                              hipStream_t stream) {
  const float* pic    = (const float*)d_in[0];
  const float* ctx    = (const float*)d_in[1];
  const float* gamma  = (const float*)d_in[2];
  const float* lnbeta = (const float*)d_in[3];
  const float* Wp     = (const float*)d_in[4];
  const float* bp     = (const float*)d_in[5];
  const float* Wc     = (const float*)d_in[6];
  const float* bc     = (const float*)d_in[7];
  const float* c1w    = (const float*)d_in[8];
  const float* c1b    = (const float*)d_in[9];
  const float* c2w    = (const float*)d_in[10];
  const float* c2b    = (const float*)d_in[11];
  const float* fcw    = (const float*)d_in[12];
  const float* fcb    = (const float*)d_in[13];
  float* out = (float*)d_out;

  if (ws_size < WS_NEED) return;

  char* ws = (char*)d_ws;
  double* stats = (double*)(ws + STATS_OFF);
  ushort* Wb    = (ushort*)(ws + WB_OFF);
  float* P      = (float*)(ws + P_OFF);
  float* out2   = (float*)(ws + OUT2_OFF);
  float* ipsum  = (float*)(ws + IPSUM_OFF);
  float* ctxbuf = (float*)(ws + CTXB_OFF);
  float* o2buf  = (float*)(ws + O2_OFF);

  hipMemsetAsync(stats, 0, 256, stream);
  hipMemsetAsync(o2buf, 0, 512 * 4, stream);
  k_wconv<<<1024, 256, 0, stream>>>(Wp, Wc, Wb);
  k_stats<<<2048, 256, 0, stream>>>(pic, ctx, stats);
  k_gemm<<<dim3(16, KSPLIT, 2), 256, 0, stream>>>(pic, ctx, gamma, lnbeta, Wb, stats, P);
  k_row<<<NROWS, 128, 0, stream>>>(P, bp, bc, out2, ipsum, ctxbuf);
  k_mid<<<8, 512, 0, stream>>>(out2, c1w, c1b, c2w, c2b, o2buf);
  k_final<<<512, 64, 0, stream>>>(o2buf, fcw, fcb, ipsum, ctxbuf, out);
}